// Round 1
// baseline (444.835 us; speedup 1.0000x reference)
//
#include <hip/hip_runtime.h>
#include <stdint.h>
#include <stddef.h>

#define NB 2
#define SEQ 2048
#define HIDN 1024
#define NHEAD 16
#define HDIM 64
#define MTOT (NB * SEQ)   // 4096

typedef short bf16x8 __attribute__((ext_vector_type(8)));
typedef float f32x4 __attribute__((ext_vector_type(4)));

__device__ __forceinline__ unsigned short f2bf(float f) {
  union { float f; uint32_t u; } v; v.f = f;
  uint32_t u = v.u;
  uint32_t r = (u + 0x7fffu + ((u >> 16) & 1u)) >> 16;
  return (unsigned short)r;
}

__device__ __forceinline__ void gload16(const void* g, void* l) {
  __builtin_amdgcn_global_load_lds((const __attribute__((address_space(1))) void*)g,
                                   (__attribute__((address_space(3))) void*)l,
                                   16, 0, 0);
}

// ---------------- kernel 1: fp32 -> bf16 conversion ----------------
// dst layout (ushort elems): xb[4194304] wqb[1048576] wkb[1048576] wvb[1048576]
__global__ void cvt_bf16(const float* __restrict__ x, const float* __restrict__ wq,
                         const float* __restrict__ wk, const float* __restrict__ wv,
                         unsigned short* __restrict__ dst)
{
  size_t i4 = ((size_t)blockIdx.x * blockDim.x + threadIdx.x) * 4;
  const float* s; size_t off;
  if (i4 < 4194304UL)      { s = x;  off = i4; }
  else if (i4 < 5242880UL) { s = wq; off = i4 - 4194304UL; }
  else if (i4 < 6291456UL) { s = wk; off = i4 - 5242880UL; }
  else                     { s = wv; off = i4 - 6291456UL; }
  float4 v = *(const float4*)(s + off);
  ushort4 o;
  o.x = f2bf(v.x); o.y = f2bf(v.y); o.z = f2bf(v.z); o.w = f2bf(v.w);
  *(ushort4*)(dst + i4) = o;
}

// ---------------- kernel 2: QKV projection GEMM (NT, bf16 MFMA) ----------------
// C[i,j] = sum_k xb[i,k] * W[j,k];  z selects {wq->Qb, wk->Kb, wv->Vt (transposed)}
__global__ __launch_bounds__(256, 2) void qkv_gemm(
    const unsigned short* __restrict__ xb,
    const unsigned short* __restrict__ wqb,
    const unsigned short* __restrict__ wkb,
    const unsigned short* __restrict__ wvb,
    unsigned short* __restrict__ Qb,
    unsigned short* __restrict__ Kb,
    unsigned short* __restrict__ Vt)
{
  __shared__ unsigned short As[128 * 64];
  __shared__ unsigned short Bs[128 * 64];

  const int z = blockIdx.z;
  const unsigned short* W = (z == 0) ? wqb : (z == 1) ? wkb : wvb;
  const int n0 = blockIdx.x * 128;
  const int m0 = blockIdx.y * 128;
  const int tid = threadIdx.x;
  const int lane = tid & 63;
  const int wid = tid >> 6;
  const int l15 = lane & 15;
  const int lg = lane >> 4;

  f32x4 acc[4][4] = {};

  const int wr = (wid >> 1) * 64;
  const int wc = (wid & 1) * 64;

  for (int kt = 0; kt < 16; ++kt) {
    __syncthreads();
    #pragma unroll
    for (int i = 0; i < 4; ++i) {
      int row = wid * 32 + i * 8 + (lane >> 3);
      int chunk = (lane & 7) ^ (row & 7);   // inverse-swizzled global source
      const unsigned short* ga = xb + (size_t)(m0 + row) * HIDN + kt * 64 + chunk * 8;
      const unsigned short* gb = W  + (size_t)(n0 + row) * HIDN + kt * 64 + chunk * 8;
      gload16(ga, (char*)As + wid * 4096 + i * 1024);
      gload16(gb, (char*)Bs + wid * 4096 + i * 1024);
    }
    __syncthreads();

    #pragma unroll
    for (int ks = 0; ks < 2; ++ks) {
      bf16x8 af[4], bfr[4];
      #pragma unroll
      for (int mi = 0; mi < 4; ++mi) {
        int row = wr + mi * 16 + l15;
        int cb = (ks * 64 + lg * 16) ^ ((row & 7) << 4);   // swizzled read
        af[mi] = *(const bf16x8*)((const char*)As + row * 128 + cb);
      }
      #pragma unroll
      for (int ni = 0; ni < 4; ++ni) {
        int row = wc + ni * 16 + l15;
        int cb = (ks * 64 + lg * 16) ^ ((row & 7) << 4);
        bfr[ni] = *(const bf16x8*)((const char*)Bs + row * 128 + cb);
      }
      #pragma unroll
      for (int mi = 0; mi < 4; ++mi)
        #pragma unroll
        for (int ni = 0; ni < 4; ++ni)
          acc[mi][ni] = __builtin_amdgcn_mfma_f32_16x16x32_bf16(af[mi], bfr[ni], acc[mi][ni], 0, 0, 0);
    }
  }

  if (z < 2) {
    unsigned short* O = (z == 0) ? Qb : Kb;
    #pragma unroll
    for (int mi = 0; mi < 4; ++mi)
      #pragma unroll
      for (int ni = 0; ni < 4; ++ni) {
        int n = n0 + wc + ni * 16 + l15;
        #pragma unroll
        for (int e = 0; e < 4; ++e) {
          int m = m0 + wr + mi * 16 + lg * 4 + e;
          O[(size_t)m * HIDN + n] = f2bf(acc[mi][ni][e]);
        }
      }
  } else {
    // V transposed: Vt[col][row], col = output channel, row = token
    #pragma unroll
    for (int mi = 0; mi < 4; ++mi)
      #pragma unroll
      for (int ni = 0; ni < 4; ++ni) {
        int n = n0 + wc + ni * 16 + l15;
        int m = m0 + wr + mi * 16 + lg * 4;
        ushort4 pk;
        pk.x = f2bf(acc[mi][ni][0]);
        pk.y = f2bf(acc[mi][ni][1]);
        pk.z = f2bf(acc[mi][ni][2]);
        pk.w = f2bf(acc[mi][ni][3]);
        *(ushort4*)(Vt + (size_t)n * MTOT + m) = pk;
      }
  }
}

// ---------------- kernel 3: fused attention ----------------
// block = (b, h, 32 q-rows); 8 waves = 2 q-halves x 4 key-groups (512 keys each)
__global__ __launch_bounds__(512, 2) void attn_fused(
    const unsigned short* __restrict__ Qb,
    const unsigned short* __restrict__ Kb,
    const unsigned short* __restrict__ Vt,
    float* __restrict__ out)
{
  __shared__ unsigned short Plds[8][16 * 136];   // per-wave padded P chunk (16 q x 128 k + pad)
  __shared__ float pvred[2][4][16][64];          // cross-wave PV reduce
  __shared__ float redmax[4][32];
  __shared__ float redsum[4][32];
  __shared__ float rowinv[32];

  const int bid = blockIdx.x;
  const int qb = bid & 63;
  const int h = (bid >> 6) & 15;
  const int b = bid >> 10;
  const int tid = threadIdx.x;
  const int lane = tid & 63;
  const int wid = tid >> 6;
  const int qh = wid >> 2;
  const int kg = wid & 3;
  const int l15 = lane & 15;
  const int lg = lane >> 4;

  const int q0 = qb * 32 + qh * 16;   // first q row (within batch) of this wave

  // Q fragments (A operand: lane holds row l15, 8 contiguous d)
  const unsigned short* qptr = Qb + (size_t)(b * SEQ + q0 + l15) * HIDN + h * HDIM + lg * 8;
  bf16x8 aq0 = *(const bf16x8*)qptr;
  bf16x8 aq1 = *(const bf16x8*)(qptr + 32);

  f32x4 acc[32] = {};

  // QK^T : B operand = K row-major (lane holds key l15, 8 contiguous d)
  const unsigned short* kptr = Kb + (size_t)(b * SEQ + kg * 512 + l15) * HIDN + h * HDIM + lg * 8;
  #pragma unroll
  for (int kf = 0; kf < 32; ++kf) {
    bf16x8 bk0 = *(const bf16x8*)(kptr + (size_t)kf * 16 * HIDN);
    bf16x8 bk1 = *(const bf16x8*)(kptr + (size_t)kf * 16 * HIDN + 32);
    acc[kf] = __builtin_amdgcn_mfma_f32_16x16x32_bf16(aq0, bk0, acc[kf], 0, 0, 0);
    acc[kf] = __builtin_amdgcn_mfma_f32_16x16x32_bf16(aq1, bk1, acc[kf], 0, 0, 0);
  }

  // ---- softmax (logit layout: key = l15, q = lg*4+e) ----
  float mx[4];
  #pragma unroll
  for (int e = 0; e < 4; ++e) mx[e] = acc[0][e];
  #pragma unroll
  for (int kf = 1; kf < 32; ++kf)
    #pragma unroll
    for (int e = 0; e < 4; ++e) mx[e] = fmaxf(mx[e], acc[kf][e]);
  for (int off = 1; off < 16; off <<= 1) {
    #pragma unroll
    for (int e = 0; e < 4; ++e) mx[e] = fmaxf(mx[e], __shfl_xor(mx[e], off, 64));
  }
  {
    float vsel = (l15 == 0) ? mx[0] : (l15 == 1) ? mx[1] : (l15 == 2) ? mx[2] : mx[3];
    if (l15 < 4) redmax[kg][qh * 16 + lg * 4 + l15] = vsel;
  }
  __syncthreads();
  float M[4];
  #pragma unroll
  for (int e = 0; e < 4; ++e) {
    int r = qh * 16 + lg * 4 + e;
    M[e] = fmaxf(fmaxf(redmax[0][r], redmax[1][r]), fmaxf(redmax[2][r], redmax[3][r]));
  }

  const float CE = 0.125f * 1.4426950408889634f;  // scale 1/sqrt(64) folded into exp2
  float sm[4] = {0.f, 0.f, 0.f, 0.f};
  #pragma unroll
  for (int kf = 0; kf < 32; ++kf)
    #pragma unroll
    for (int e = 0; e < 4; ++e) {
      float p = exp2f((acc[kf][e] - M[e]) * CE);
      acc[kf][e] = p;
      sm[e] += p;
    }
  for (int off = 1; off < 16; off <<= 1) {
    #pragma unroll
    for (int e = 0; e < 4; ++e) sm[e] += __shfl_xor(sm[e], off, 64);
  }
  {
    float vsel = (l15 == 0) ? sm[0] : (l15 == 1) ? sm[1] : (l15 == 2) ? sm[2] : sm[3];
    if (l15 < 4) redsum[kg][qh * 16 + lg * 4 + l15] = vsel;
  }
  __syncthreads();
  float inv[4];
  #pragma unroll
  for (int e = 0; e < 4; ++e) {
    int r = qh * 16 + lg * 4 + e;
    float T = redsum[0][r] + redsum[1][r] + redsum[2][r] + redsum[3][r];
    inv[e] = __builtin_amdgcn_rcpf(T);
  }

  // ---- score write + P transpose through LDS + PV MFMA ----
  f32x4 pv[4] = {};
  const size_t sbase = (size_t)(b * NHEAD + h) * SEQ * SEQ;
  unsigned short* pl = &Plds[wid][0];
  const unsigned short* vptr = Vt + (size_t)(h * HDIM + l15) * MTOT + b * SEQ + kg * 512 + lg * 8;

  #pragma unroll
  for (int c = 0; c < 4; ++c) {
    #pragma unroll
    for (int kf8 = 0; kf8 < 8; ++kf8) {
      int kf = c * 8 + kf8;
      #pragma unroll
      for (int e = 0; e < 4; ++e) {
        float p = acc[kf][e];
        out[sbase + (size_t)(q0 + lg * 4 + e) * SEQ + kg * 512 + kf * 16 + l15] = p * inv[e];
        pl[(lg * 4 + e) * 136 + kf8 * 16 + l15] = f2bf(p);  // unnormalized; scale at end
      }
    }
    #pragma unroll
    for (int ks = 0; ks < 4; ++ks) {
      bf16x8 af = *(const bf16x8*)((const char*)pl + l15 * 272 + ks * 64 + lg * 16);
      #pragma unroll
      for (int nf = 0; nf < 4; ++nf) {
        bf16x8 bv = *(const bf16x8*)(vptr + (size_t)nf * 16 * MTOT + c * 128 + ks * 32);
        pv[nf] = __builtin_amdgcn_mfma_f32_16x16x32_bf16(af, bv, pv[nf], 0, 0, 0);
      }
    }
  }

  // ---- cross-wave PV reduction ----
  #pragma unroll
  for (int nf = 0; nf < 4; ++nf)
    #pragma unroll
    for (int e = 0; e < 4; ++e)
      pvred[qh][kg][lg * 4 + e][nf * 16 + l15] = pv[nf][e];
  {
    float vsel = (l15 == 0) ? inv[0] : (l15 == 1) ? inv[1] : (l15 == 2) ? inv[2] : inv[3];
    if (kg == 0 && l15 < 4) rowinv[qh * 16 + lg * 4 + l15] = vsel;
  }
  __syncthreads();

  {
    int row = tid >> 4;        // 0..31
    int dq = tid & 15;         // d = dq*4
    float4 s = {0.f, 0.f, 0.f, 0.f};
    #pragma unroll
    for (int k2 = 0; k2 < 4; ++k2) {
      float4 t = *(const float4*)&pvred[row >> 4][k2][row & 15][dq << 2];
      s.x += t.x; s.y += t.y; s.z += t.z; s.w += t.w;
    }
    float iv = rowinv[row];
    s.x *= iv; s.y *= iv; s.z *= iv; s.w *= iv;
    float* av = out + (size_t)NB * NHEAD * SEQ * SEQ;
    size_t o = ((size_t)(b * NHEAD + h) * SEQ + qb * 32 + row) * HDIM + (dq << 2);
    *(float4*)&av[o] = s;
  }
}

extern "C" void kernel_launch(void* const* d_in, const int* in_sizes, int n_in,
                              void* d_out, int out_size, void* d_ws, size_t ws_size,
                              hipStream_t stream)
{
  const float* x  = (const float*)d_in[0];
  const float* wq = (const float*)d_in[1];
  const float* wk = (const float*)d_in[2];
  const float* wv = (const float*)d_in[3];
  float* out = (float*)d_out;
  unsigned short* ws = (unsigned short*)d_ws;

  // ws layout (ushort elems): xb | wqb | wkb | wvb | Qb | Kb | Vt  (~38 MB)
  unsigned short* xb  = ws;
  unsigned short* wqb = ws + 4194304;
  unsigned short* wkb = ws + 5242880;
  unsigned short* wvb = ws + 6291456;
  unsigned short* Qb  = ws + 7340032;
  unsigned short* Kb  = ws + 11534336;
  unsigned short* Vt  = ws + 15728640;

  cvt_bf16<<<7168, 256, 0, stream>>>(x, wq, wk, wv, ws);
  qkv_gemm<<<dim3(8, 32, 3), 256, 0, stream>>>(xb, wqb, wkb, wvb, Qb, Kb, Vt);
  attn_fused<<<2048, 512, 0, stream>>>(Qb, Kb, Vt, out);
}